// Round 2
// baseline (934.773 us; speedup 1.0000x reference)
//
#include <hip/hip_runtime.h>

#define N_NODES 100000
#define N_EDGES 3200000
#define IN_DIM 128
#define HID 64

typedef __attribute__((ext_vector_type(8))) short short8;
typedef __attribute__((ext_vector_type(4))) float f32x4;

// round-to-nearest-even fp32 -> bf16 (stored in short)
__device__ inline short f2bf_s(float f) {
    union { float f; unsigned int u; } c;
    c.f = f;
    unsigned int u = c.u;
    return (short)((u + 0x7fffu + ((u >> 16) & 1u)) >> 16);
}

// load 8 contiguous floats, convert to bf16x8 fragment
__device__ inline short8 cvt8(const float* __restrict__ p) {
    f32x4 lo = *reinterpret_cast<const f32x4*>(p);
    f32x4 hi = *reinterpret_cast<const f32x4*>(p + 4);
    short8 r;
#pragma unroll
    for (int j = 0; j < 4; ++j) { r[j] = f2bf_s(lo[j]); r[4 + j] = f2bf_s(hi[j]); }
    return r;
}

// ---------------------------------------------------------------------------
// fc + relu: h0[i,j] = relu(sum_k x[i,k] * W[j,k] + b[j]);  x:[N,128] W:[64,128]
// One wave computes a 16-node x 64-feature tile via 16 MFMAs (4 ksteps x 4 ntiles).
// A frag: x[m=lane&15][k=quad*8+j]  -> contiguous load (row-major x), cvt to bf16.
// B frag: (W^T)[k][n] = W[n=lane&15][k=quad*8+j] -> contiguous load of W row.
// D: col=lane&15 (out feature), row=quad*4+reg (node).  fp32 in/out.
// ---------------------------------------------------------------------------
__global__ __launch_bounds__(256) void fc_kernel(
    const float* __restrict__ x, const float* __restrict__ W,
    const float* __restrict__ b, float* __restrict__ h0) {
    int lane = threadIdx.x & 63;
    int wtile = (int)((blockIdx.x * blockDim.x + threadIdx.x) >> 6);
    const int tile_cnt = N_NODES / 16;  // 6250, exact
    if (wtile >= tile_cnt) return;
    int col = lane & 15, quad = lane >> 4;

    short8 bw[4][4];
#pragma unroll
    for (int nt = 0; nt < 4; ++nt)
#pragma unroll
        for (int ks = 0; ks < 4; ++ks)
            bw[nt][ks] = cvt8(W + (nt * 16 + col) * IN_DIM + ks * 32 + quad * 8);

    f32x4 acc[4];
#pragma unroll
    for (int nt = 0; nt < 4; ++nt) acc[nt] = {0.f, 0.f, 0.f, 0.f};

    int node0 = wtile * 16;
    const float* xrow = x + (size_t)(node0 + col) * IN_DIM + quad * 8;
#pragma unroll
    for (int ks = 0; ks < 4; ++ks) {
        short8 a = cvt8(xrow + ks * 32);
#pragma unroll
        for (int nt = 0; nt < 4; ++nt)
            acc[nt] = __builtin_amdgcn_mfma_f32_16x16x32_bf16(a, bw[nt][ks], acc[nt], 0, 0, 0);
    }

#pragma unroll
    for (int nt = 0; nt < 4; ++nt) {
        float bias = b[nt * 16 + col];
#pragma unroll
        for (int r = 0; r < 4; ++r) {
            float v = acc[nt][r] + bias;
            v = v > 0.f ? v : 0.f;
            h0[(size_t)(node0 + quad * 4 + r) * HID + nt * 16 + col] = v;
        }
    }
}

// ---------------------------------------------------------------------------
// SAGE linear: hout = (agg @ Wl^T + bl) + (hin @ Wr^T)  [+ relu]
// Same MFMA tiling; K=64 -> 2 ksteps per weight matrix. fp32 in/out.
// ---------------------------------------------------------------------------
__global__ __launch_bounds__(256) void sage_kernel(
    const float* __restrict__ agg, const float* __restrict__ hin,
    const float* __restrict__ Wl, const float* __restrict__ bl,
    const float* __restrict__ Wr, float* __restrict__ hout, int do_relu) {
    int lane = threadIdx.x & 63;
    int wtile = (int)((blockIdx.x * blockDim.x + threadIdx.x) >> 6);
    const int tile_cnt = N_NODES / 16;
    if (wtile >= tile_cnt) return;
    int col = lane & 15, quad = lane >> 4;

    short8 bwl[4][2], bwr[4][2];
#pragma unroll
    for (int nt = 0; nt < 4; ++nt)
#pragma unroll
        for (int ks = 0; ks < 2; ++ks) {
            bwl[nt][ks] = cvt8(Wl + (nt * 16 + col) * HID + ks * 32 + quad * 8);
            bwr[nt][ks] = cvt8(Wr + (nt * 16 + col) * HID + ks * 32 + quad * 8);
        }

    f32x4 acc[4];
#pragma unroll
    for (int nt = 0; nt < 4; ++nt) acc[nt] = {0.f, 0.f, 0.f, 0.f};

    int node0 = wtile * 16;
    const float* arow = agg + (size_t)(node0 + col) * HID + quad * 8;
    const float* hrow = hin + (size_t)(node0 + col) * HID + quad * 8;
#pragma unroll
    for (int ks = 0; ks < 2; ++ks) {
        short8 aA = cvt8(arow + ks * 32);
#pragma unroll
        for (int nt = 0; nt < 4; ++nt)
            acc[nt] = __builtin_amdgcn_mfma_f32_16x16x32_bf16(aA, bwl[nt][ks], acc[nt], 0, 0, 0);
        short8 aH = cvt8(hrow + ks * 32);
#pragma unroll
        for (int nt = 0; nt < 4; ++nt)
            acc[nt] = __builtin_amdgcn_mfma_f32_16x16x32_bf16(aH, bwr[nt][ks], acc[nt], 0, 0, 0);
    }

#pragma unroll
    for (int nt = 0; nt < 4; ++nt) {
        float bias = bl[nt * 16 + col];
#pragma unroll
        for (int r = 0; r < 4; ++r) {
            float v = acc[nt][r] + bias;
            if (do_relu) v = v > 0.f ? v : 0.f;
            hout[(size_t)(node0 + quad * 4 + r) * HID + nt * 16 + col] = v;
        }
    }
}

// ---------------------------------------------------------------------------
// CSR build: degree count -> single-block scan -> positioned fill
// ---------------------------------------------------------------------------
__global__ void count_deg(const int* __restrict__ ei, int* __restrict__ deg) {
    int e = blockIdx.x * blockDim.x + threadIdx.x;
    if (e < N_EDGES) atomicAdd(&deg[ei[N_EDGES + e]], 1);
}

__global__ __launch_bounds__(1024) void scan_kernel(
    const int* __restrict__ deg, int* __restrict__ row_ptr, int* __restrict__ fill_ptr) {
    __shared__ int wsum[16];
    __shared__ int woff[16];
    __shared__ int running_s;
    int t = threadIdx.x, lane = t & 63, wid = t >> 6;
    if (t == 0) running_s = 0;
    __syncthreads();
    for (int base = 0; base < N_NODES; base += 1024) {
        int i = base + t;
        int v = (i < N_NODES) ? deg[i] : 0;
        int s = v;
#pragma unroll
        for (int d = 1; d < 64; d <<= 1) {
            int n = __shfl_up(s, d);
            if (lane >= d) s += n;
        }
        if (lane == 63) wsum[wid] = s;
        __syncthreads();
        if (t == 0) {
            int r = running_s;
#pragma unroll
            for (int w = 0; w < 16; ++w) { woff[w] = r; r += wsum[w]; }
            running_s = r;
        }
        __syncthreads();
        int excl = woff[wid] + s - v;
        if (i < N_NODES) { row_ptr[i] = excl; fill_ptr[i] = excl; }
    }
    if (threadIdx.x == 0) { row_ptr[N_NODES] = running_s; fill_ptr[N_NODES] = running_s; }
}

__global__ void fill_csr(const int* __restrict__ ei, int* __restrict__ fptr,
                         int* __restrict__ csr) {
    int e = blockIdx.x * blockDim.x + threadIdx.x;
    if (e < N_EDGES) {
        int dst = ei[N_EDGES + e];
        int src = ei[e];
        int pos = atomicAdd(&fptr[dst], 1);
        csr[pos] = src;
    }
}

// ---------------------------------------------------------------------------
// Mean aggregation: wave per node, lane = feature (fp32, 256B coalesced rows).
// Register accumulation, 4-way unroll for memory-level parallelism.
// ---------------------------------------------------------------------------
__global__ __launch_bounds__(256) void agg_kernel(
    const float* __restrict__ h, const int* __restrict__ row_ptr,
    const int* __restrict__ csr, float* __restrict__ out) {
    int lane = threadIdx.x & 63;
    int node = (int)((blockIdx.x * blockDim.x + threadIdx.x) >> 6);
    if (node >= N_NODES) return;
    int s = row_ptr[node], e = row_ptr[node + 1];
    float a0 = 0.f, a1 = 0.f, a2 = 0.f, a3 = 0.f;
    int p = s;
    for (; p + 4 <= e; p += 4) {
        int i0 = csr[p], i1 = csr[p + 1], i2 = csr[p + 2], i3 = csr[p + 3];
        a0 += h[(size_t)i0 * HID + lane];
        a1 += h[(size_t)i1 * HID + lane];
        a2 += h[(size_t)i2 * HID + lane];
        a3 += h[(size_t)i3 * HID + lane];
    }
    for (; p < e; ++p) a0 += h[(size_t)csr[p] * HID + lane];
    float acc = (a0 + a1) + (a2 + a3);
    int deg = e - s;
    float inv = deg > 0 ? 1.f / (float)deg : 0.f;
    out[(size_t)node * HID + lane] = acc * inv;
}

// ---------------------------------------------------------------------------
// head: out[i] = dot(h2[i,:], head_W) + head_b   (wave per node, shuffle reduce)
// ---------------------------------------------------------------------------
__global__ __launch_bounds__(256) void head_kernel(
    const float* __restrict__ h2, const float* __restrict__ hw,
    const float* __restrict__ hb, float* __restrict__ out) {
    int lane = threadIdx.x & 63;
    int node = (int)((blockIdx.x * blockDim.x + threadIdx.x) >> 6);
    if (node >= N_NODES) return;
    float v = h2[(size_t)node * HID + lane] * hw[lane];
#pragma unroll
    for (int d = 32; d > 0; d >>= 1) v += __shfl_xor(v, d);
    if (lane == 0) out[node] = v + hb[0];
}

extern "C" void kernel_launch(void* const* d_in, const int* in_sizes, int n_in,
                              void* d_out, int out_size, void* d_ws, size_t ws_size,
                              hipStream_t stream) {
    const float* x   = (const float*)d_in[0];
    const int*   ei  = (const int*)d_in[1];
    // d_in[2] = batch (unused: single graph, per-node head output)
    const float* fcW = (const float*)d_in[3];
    const float* fcb = (const float*)d_in[4];
    const float* Wl1 = (const float*)d_in[5];
    const float* bl1 = (const float*)d_in[6];
    const float* Wr1 = (const float*)d_in[7];
    const float* Wl2 = (const float*)d_in[8];
    const float* bl2 = (const float*)d_in[9];
    const float* Wr2 = (const float*)d_in[10];
    const float* hW  = (const float*)d_in[11];
    const float* hb  = (const float*)d_in[12];
    float* out = (float*)d_out;

    char* ws = (char*)d_ws;
    size_t off = 0;
    auto alloc = [&](size_t bytes) -> char* {
        char* p = ws + off;
        off = (off + bytes + 255) & ~(size_t)255;
        return p;
    };
    float* h0     = (float*)alloc((size_t)N_NODES * HID * 4);
    float* h1     = (float*)alloc((size_t)N_NODES * HID * 4);
    float* agg    = (float*)alloc((size_t)N_NODES * HID * 4);
    int* deg      = (int*)alloc((size_t)N_NODES * 4);
    int* row_ptr  = (int*)alloc((size_t)(N_NODES + 1) * 4);
    int* fill_ptr = (int*)alloc((size_t)(N_NODES + 1) * 4);
    int* csr      = (int*)alloc((size_t)N_EDGES * 4);
    float* h2     = h0;  // h0 dead after sage1; reuse for layer-2 output

    const int lin_blocks = (N_NODES / 16 + 3) / 4;   // 4 waves/block, 1 tile/wave
    const int edge_blocks = (N_EDGES + 255) / 256;
    const int node_wave_blocks = (N_NODES + 3) / 4;  // 4 waves/block, 1 node/wave

    hipMemsetAsync(deg, 0, (size_t)N_NODES * 4, stream);
    fc_kernel<<<lin_blocks, 256, 0, stream>>>(x, fcW, fcb, h0);
    count_deg<<<edge_blocks, 256, 0, stream>>>(ei, deg);
    scan_kernel<<<1, 1024, 0, stream>>>(deg, row_ptr, fill_ptr);
    fill_csr<<<edge_blocks, 256, 0, stream>>>(ei, fill_ptr, csr);
    agg_kernel<<<node_wave_blocks, 256, 0, stream>>>(h0, row_ptr, csr, agg);
    sage_kernel<<<lin_blocks, 256, 0, stream>>>(agg, h0, Wl1, bl1, Wr1, h1, 1);
    agg_kernel<<<node_wave_blocks, 256, 0, stream>>>(h1, row_ptr, csr, agg);
    sage_kernel<<<lin_blocks, 256, 0, stream>>>(agg, h1, Wl2, bl2, Wr2, h2, 0);
    head_kernel<<<node_wave_blocks, 256, 0, stream>>>(h2, hW, hb, out);
}